// Round 6
// baseline (166.094 us; speedup 1.0000x reference)
//
#include <hip/hip_runtime.h>
#include <stdint.h>

#define B_ROWS 32768
#define N_INP 256
#define N_HID 1024
#define NF 256
#define N_IT 100

typedef __attribute__((ext_vector_type(8))) _Float16 f16x8;
typedef __attribute__((ext_vector_type(4))) float f32x4;
typedef __attribute__((ext_vector_type(2))) float f32x2;

__device__ __forceinline__ ushort f2h(float f) {
  _Float16 h = (_Float16)f;               // v_cvt_f16_f32, RNE
  return *reinterpret_cast<ushort*>(&h);
}

__device__ __forceinline__ void async_copy16(const void* g, void* l) {
  __builtin_amdgcn_global_load_lds(
      (const __attribute__((address_space(1))) void*)g,
      (__attribute__((address_space(3))) void*)l, 16, 0, 0);
}

// VOP3P packed f32 (CDNA): one instruction does both components.
// NOTE: no packed f32 min exists; min stays scalar. NO OMOD anywhere
// (OMOD is ignored in IEEE mode -> round-5 failure).
__device__ __forceinline__ f32x2 pk_add(f32x2 a, f32x2 b) {
  f32x2 r;
  asm("v_pk_add_f32 %0, %1, %2" : "=v"(r) : "v"(a), "v"(b));
  return r;
}
__device__ __forceinline__ f32x2 pk_mul(f32x2 a, f32x2 b) {
  f32x2 r;
  asm("v_pk_mul_f32 %0, %1, %2" : "=v"(r) : "v"(a), "v"(b));
  return r;
}

// ---- prepass (fused): pack x -> f16 [B,256] + idx; convert W1/W2 -> f16 ----
__global__ void prep_kernel(const float* __restrict__ x,
                            const float* __restrict__ W1,
                            const float* __restrict__ W2,
                            ushort* __restrict__ xh,
                            ushort* __restrict__ w1h,
                            ushort* __restrict__ w2h,
                            int* __restrict__ idx) {
  if (blockIdx.x < 8192) {
    int t = blockIdx.x * 256 + threadIdx.x;          // B*64 threads
    int b = t >> 6, q = t & 63;
    const float* xr = x + (size_t)b * (N_INP + 1);
    float v0 = xr[q * 4 + 0], v1 = xr[q * 4 + 1], v2 = xr[q * 4 + 2], v3 = xr[q * 4 + 3];
    ushort4 u = make_ushort4(f2h(v0), f2h(v1), f2h(v2), f2h(v3));
    *reinterpret_cast<ushort4*>(xh + (size_t)b * 256 + q * 4) = u;
    if (q == 0) idx[b] = (int)rintf(xr[N_INP] * 255.0f);
  } else {
    int t = (blockIdx.x - 8192) * 256 + threadIdx.x; // 65536 threads
    float4 a = reinterpret_cast<const float4*>(W1)[t];
    float4 b = reinterpret_cast<const float4*>(W2)[t];
    reinterpret_cast<ushort4*>(w1h)[t] = make_ushort4(f2h(a.x), f2h(a.y), f2h(a.z), f2h(a.w));
    reinterpret_cast<ushort4*>(w2h)[t] = make_ushort4(f2h(b.x), f2h(b.y), f2h(b.z), f2h(b.w));
  }
}

// ---- C[M,N] = epi(A[M,K] @ Bw[N,K]^T + bias), f16 output ----
template <int RELU>
__global__ __launch_bounds__(256, 2) void gemm_bt(
    const ushort* __restrict__ A, const ushort* __restrict__ Bw,
    const float* __restrict__ bias, ushort* __restrict__ C,
    int M, int N, int K, int ntN) {
  __shared__ ushort As[2][128 * 64];
  __shared__ ushort Bs[2][128 * 64];
  const int tid = threadIdx.x;
  const int w = tid >> 6, l = tid & 63;
  // bijective XCD swizzle (grid%8==0 in all our launches)
  int bid = blockIdx.x;
  if (((int)gridDim.x & 7) == 0) {
    int cpx = (int)gridDim.x >> 3;
    bid = (bid & 7) * cpx + (bid >> 3);
  }
  const int tm = bid / ntN, tn = bid % ntN;
  const int wm = w >> 1, wn = w & 1;
  const char* Ab = (const char*)(A + (size_t)tm * 128 * K);
  const char* Bb = (const char*)(Bw + (size_t)tn * 128 * K);
  const int sA = K * 2;
  const int lrow = l >> 3;
  const int lcol = (l & 7) * 16;

  f32x4 acc[4][4];
#pragma unroll
  for (int i = 0; i < 4; ++i)
#pragma unroll
    for (int j = 0; j < 4; ++j) acc[i][j] = {0.f, 0.f, 0.f, 0.f};

  const int nkt = K / 64;
  {  // prologue stage kt=0
    const char* ga = Ab + lrow * sA + lcol;
    const char* gb = Bb + lrow * sA + lcol;
#pragma unroll
    for (int i = 0; i < 4; ++i) {
      int c = w * 4 + i;
      async_copy16(ga + c * 8 * sA, (char*)&As[0][0] + c * 1024);
      async_copy16(gb + c * 8 * sA, (char*)&Bs[0][0] + c * 1024);
    }
  }
  __syncthreads();

  const int arow = wm * 64 + (l & 15);
  const int brow = wn * 64 + (l & 15);
  const int koff = (l >> 4) * 8;

  for (int kt = 0; kt < nkt; ++kt) {
    const int buf = kt & 1;
    if (kt + 1 < nkt) {
      const char* ga = Ab + (kt + 1) * 128 + lrow * sA + lcol;
      const char* gb = Bb + (kt + 1) * 128 + lrow * sA + lcol;
#pragma unroll
      for (int i = 0; i < 4; ++i) {
        int c = w * 4 + i;
        async_copy16(ga + c * 8 * sA, (char*)&As[buf ^ 1][0] + c * 1024);
        async_copy16(gb + c * 8 * sA, (char*)&Bs[buf ^ 1][0] + c * 1024);
      }
    }
#pragma unroll
    for (int ks = 0; ks < 2; ++ks) {
      f16x8 af[4], bfr[4];
#pragma unroll
      for (int mi = 0; mi < 4; ++mi)
        af[mi] = *(const f16x8*)&As[buf][(arow + mi * 16) * 64 + ks * 32 + koff];
#pragma unroll
      for (int ni = 0; ni < 4; ++ni)
        bfr[ni] = *(const f16x8*)&Bs[buf][(brow + ni * 16) * 64 + ks * 32 + koff];
#pragma unroll
      for (int mi = 0; mi < 4; ++mi)
#pragma unroll
        for (int ni = 0; ni < 4; ++ni)
          acc[mi][ni] = __builtin_amdgcn_mfma_f32_16x16x32_f16(
              af[mi], bfr[ni], acc[mi][ni], 0, 0, 0);
    }
    __syncthreads();
  }

  const int grow0 = tm * 128 + wm * 64 + (l >> 4) * 4;
  const int gcol0 = tn * 128 + wn * 64 + (l & 15);
#pragma unroll
  for (int ni = 0; ni < 4; ++ni) {
    const int col = gcol0 + ni * 16;
    const float bv = bias[col];
#pragma unroll
    for (int mi = 0; mi < 4; ++mi) {
      const int row = grow0 + mi * 16;
#pragma unroll
      for (int r = 0; r < 4; ++r) {
        float v = acc[mi][ni][r] + bv;
        if (RELU) v = fmaxf(v, 0.f);
        C[(size_t)(row + r) * N + col] = f2h(v);
      }
    }
  }
}

// ---- convex fixed-point (100 iters) + gather ----
// y-space: y_i <- min(y_i, 0.5*(y_{i-1}+y_{i+1})); result = y.
// TWO ROWS packed per f32x2 component: .x = row rA, .y = row rB = rA+4.
// 16 lanes per row-pair, 16 feats/lane -> 8 rows/wave.
// Per feature-pair: 1 v_pk_add + 1 v_pk_mul + 2 v_min (no pk f32 min on CDNA).
__global__ __launch_bounds__(256, 4) void convex_gather(
    const ushort* __restrict__ xqh, const int* __restrict__ idx,
    float* __restrict__ out) {
  const int l = threadIdx.x & 63;
  const int wv = threadIdx.x >> 6;
  const int q = l & 15;                 // lane within row-pair group
  const int g = l >> 4;                 // group 0..3
  const int base = blockIdx.x * 32 + wv * 8;
  const int rA = base + g;
  const int rB = rA + 4;

  f32x2 y[16];
  {
    const ushort* sa = xqh + (size_t)rA * 256 + q * 16;
    const ushort* sb = xqh + (size_t)rB * 256 + q * 16;
    f16x8 a0 = *reinterpret_cast<const f16x8*>(sa);
    f16x8 a1 = *reinterpret_cast<const f16x8*>(sa + 8);
    f16x8 b0 = *reinterpret_cast<const f16x8*>(sb);
    f16x8 b1 = *reinterpret_cast<const f16x8*>(sb + 8);
#pragma unroll
    for (int j = 0; j < 8; ++j) {
      y[j].x = (float)a0[j];      y[j].y = (float)b0[j];
      y[8 + j].x = (float)a1[j];  y[8 + j].y = (float)b1[j];
    }
  }
  const int iiA = idx[rA];
  const int iiB = idx[rB];

  // hoisted bpermute byte-indices; cross-group reads masked by sentinels
  // (feats 0 and 255 never update: D boundary rows are zero)
  const int upIdx = ((l - 1) & 63) * 4;
  const int dnIdx = ((l + 1) & 63) * 4;
  const float sL = (q == 0) ? 3.0e38f : 0.0f;
  const float sR = (q == 15) ? 3.0e38f : 0.0f;
  const f32x2 bLp = {sL, sL};
  const f32x2 bRp = {sR, sR};
  const f32x2 hhalf = {0.5f, 0.5f};

#pragma unroll 2
  for (int it = 0; it < N_IT; ++it) {
    f32x2 Lv, Rv;
    Lv.x = __int_as_float(__builtin_amdgcn_ds_bpermute(upIdx, __float_as_int(y[15].x)));
    Lv.y = __int_as_float(__builtin_amdgcn_ds_bpermute(upIdx, __float_as_int(y[15].y)));
    Rv.x = __int_as_float(__builtin_amdgcn_ds_bpermute(dnIdx, __float_as_int(y[0].x)));
    Rv.y = __int_as_float(__builtin_amdgcn_ds_bpermute(dnIdx, __float_as_int(y[0].y)));
    Lv = pk_add(Lv, bLp);
    Rv = pk_add(Rv, bRp);
    f32x2 m[16];
    m[0] = pk_mul(pk_add(Lv, y[1]), hhalf);
#pragma unroll
    for (int t = 1; t < 15; ++t) m[t] = pk_mul(pk_add(y[t - 1], y[t + 1]), hhalf);
    m[15] = pk_mul(pk_add(y[14], Rv), hhalf);
#pragma unroll
    for (int t = 0; t < 16; ++t) {
      y[t].x = fminf(y[t].x, m[t].x);
      y[t].y = fminf(y[t].y, m[t].y);
    }
  }

  // gather feature iiA (row rA) and iiB (row rB): cndmask trees + lane pick
  float ya[16], yb[16];
#pragma unroll
  for (int t = 0; t < 16; ++t) { ya[t] = y[t].x; yb[t] = y[t].y; }
  const int selA = iiA & 15, selB = iiB & 15;
#pragma unroll
  for (int step = 8; step >= 1; step >>= 1) {
#pragma unroll
    for (int k = 0; k < 8; ++k) {
      if (k < step) {
        ya[k] = (selA & step) ? ya[k + step] : ya[k];
        yb[k] = (selB & step) ? yb[k + step] : yb[k];
      }
    }
  }
  float vA = __shfl(ya[0], (l & ~15) | (iiA >> 4));
  float vB = __shfl(yb[0], (l & ~15) | (iiB >> 4));
  if (q == 0) {
    out[rA] = vA;
    out[rB] = vB;
  }
}

extern "C" void kernel_launch(void* const* d_in, const int* in_sizes, int n_in,
                              void* d_out, int out_size, void* d_ws, size_t ws_size,
                              hipStream_t stream) {
  const float* x = (const float*)d_in[0];
  const float* W1 = (const float*)d_in[1];
  const float* b1 = (const float*)d_in[2];
  const float* W2 = (const float*)d_in[3];
  const float* b2 = (const float*)d_in[4];
  float* out = (float*)d_out;

  // workspace layout (16B-aligned)
  char* ws = (char*)d_ws;
  ushort* xh  = (ushort*)ws;                    // 16,777,216 B  x f16 [B,256]
  ushort* w1h = (ushort*)(ws + 16777216);       //    524,288 B
  ushort* w2h = (ushort*)(ws + 17301504);       //    524,288 B
  int*    idx = (int*)  (ws + 17825792);        //    131,072 B
  ushort* xqh = (ushort*)(ws + 17956864);       // 16,777,216 B  x_ f16 [B,256]
  ushort* h   = (ushort*)(ws + 34734080);       // chunk*2048 B  h f16 [chunk,1024]

  const size_t fixed = 34734080;
  int chunk = 2048;
  if (ws_size >= fixed + (size_t)32768 * 2048) chunk = 32768;
  else if (ws_size >= fixed + (size_t)16384 * 2048) chunk = 16384;
  else if (ws_size >= fixed + (size_t)8192 * 2048) chunk = 8192;
  else if (ws_size >= fixed + (size_t)4096 * 2048) chunk = 4096;

  prep_kernel<<<8448, 256, 0, stream>>>(x, W1, W2, xh, w1h, w2h, idx);

  for (int m0 = 0; m0 < B_ROWS; m0 += chunk) {
    int curM = (B_ROWS - m0 < chunk) ? (B_ROWS - m0) : chunk;
    dim3 g1((curM / 128) * (N_HID / 128));
    gemm_bt<1><<<g1, 256, 0, stream>>>(xh + (size_t)m0 * 256, w1h, b1, h,
                                       curM, N_HID, N_INP, N_HID / 128);
    dim3 g2((curM / 128) * (NF / 128));
    gemm_bt<0><<<g2, 256, 0, stream>>>(h, w2h, b2, xqh + (size_t)m0 * 256,
                                       curM, NF, N_HID, NF / 128);
  }
  convex_gather<<<B_ROWS / 32, 256, 0, stream>>>(xqh, idx, out);
}

// Round 7
// 145.400 us; speedup vs baseline: 1.1423x; 1.1423x over previous
//
#include <hip/hip_runtime.h>
#include <stdint.h>

#define B_ROWS 32768
#define N_INP 256
#define N_HID 1024
#define NF 256
#define N_IT 100

typedef __attribute__((ext_vector_type(8))) _Float16 f16x8;
typedef __attribute__((ext_vector_type(4))) float f32x4;
typedef __attribute__((ext_vector_type(2))) float f32x2;

__device__ __forceinline__ ushort f2h(float f) {
  _Float16 h = (_Float16)f;               // v_cvt_f16_f32, RNE
  return *reinterpret_cast<ushort*>(&h);
}

__device__ __forceinline__ void async_copy16(const void* g, void* l) {
  __builtin_amdgcn_global_load_lds(
      (const __attribute__((address_space(1))) void*)g,
      (__attribute__((address_space(3))) void*)l, 16, 0, 0);
}

// ---- prepass (fused): pack x -> f16 [B,256] + idx; convert W1/W2 -> f16 ----
__global__ void prep_kernel(const float* __restrict__ x,
                            const float* __restrict__ W1,
                            const float* __restrict__ W2,
                            ushort* __restrict__ xh,
                            ushort* __restrict__ w1h,
                            ushort* __restrict__ w2h,
                            int* __restrict__ idx) {
  if (blockIdx.x < 8192) {
    int t = blockIdx.x * 256 + threadIdx.x;          // B*64 threads
    int b = t >> 6, q = t & 63;
    const float* xr = x + (size_t)b * (N_INP + 1);
    float v0 = xr[q * 4 + 0], v1 = xr[q * 4 + 1], v2 = xr[q * 4 + 2], v3 = xr[q * 4 + 3];
    ushort4 u = make_ushort4(f2h(v0), f2h(v1), f2h(v2), f2h(v3));
    *reinterpret_cast<ushort4*>(xh + (size_t)b * 256 + q * 4) = u;
    if (q == 0) idx[b] = (int)rintf(xr[N_INP] * 255.0f);
  } else {
    int t = (blockIdx.x - 8192) * 256 + threadIdx.x; // 65536 threads
    float4 a = reinterpret_cast<const float4*>(W1)[t];
    float4 b = reinterpret_cast<const float4*>(W2)[t];
    reinterpret_cast<ushort4*>(w1h)[t] = make_ushort4(f2h(a.x), f2h(a.y), f2h(a.z), f2h(a.w));
    reinterpret_cast<ushort4*>(w2h)[t] = make_ushort4(f2h(b.x), f2h(b.y), f2h(b.z), f2h(b.w));
  }
}

// ---- C[M,N] = epi(A[M,K] @ Bw[N,K]^T + bias), f16 output ----
template <int RELU>
__global__ __launch_bounds__(256, 2) void gemm_bt(
    const ushort* __restrict__ A, const ushort* __restrict__ Bw,
    const float* __restrict__ bias, ushort* __restrict__ C,
    int M, int N, int K, int ntN) {
  __shared__ ushort As[2][128 * 64];
  __shared__ ushort Bs[2][128 * 64];
  const int tid = threadIdx.x;
  const int w = tid >> 6, l = tid & 63;
  // bijective XCD swizzle (grid%8==0 in all our launches)
  int bid = blockIdx.x;
  if (((int)gridDim.x & 7) == 0) {
    int cpx = (int)gridDim.x >> 3;
    bid = (bid & 7) * cpx + (bid >> 3);
  }
  const int tm = bid / ntN, tn = bid % ntN;
  const int wm = w >> 1, wn = w & 1;
  const char* Ab = (const char*)(A + (size_t)tm * 128 * K);
  const char* Bb = (const char*)(Bw + (size_t)tn * 128 * K);
  const int sA = K * 2;
  const int lrow = l >> 3;
  const int lcol = (l & 7) * 16;

  f32x4 acc[4][4];
#pragma unroll
  for (int i = 0; i < 4; ++i)
#pragma unroll
    for (int j = 0; j < 4; ++j) acc[i][j] = {0.f, 0.f, 0.f, 0.f};

  const int nkt = K / 64;
  {  // prologue stage kt=0
    const char* ga = Ab + lrow * sA + lcol;
    const char* gb = Bb + lrow * sA + lcol;
#pragma unroll
    for (int i = 0; i < 4; ++i) {
      int c = w * 4 + i;
      async_copy16(ga + c * 8 * sA, (char*)&As[0][0] + c * 1024);
      async_copy16(gb + c * 8 * sA, (char*)&Bs[0][0] + c * 1024);
    }
  }
  __syncthreads();

  const int arow = wm * 64 + (l & 15);
  const int brow = wn * 64 + (l & 15);
  const int koff = (l >> 4) * 8;

  for (int kt = 0; kt < nkt; ++kt) {
    const int buf = kt & 1;
    if (kt + 1 < nkt) {
      const char* ga = Ab + (kt + 1) * 128 + lrow * sA + lcol;
      const char* gb = Bb + (kt + 1) * 128 + lrow * sA + lcol;
#pragma unroll
      for (int i = 0; i < 4; ++i) {
        int c = w * 4 + i;
        async_copy16(ga + c * 8 * sA, (char*)&As[buf ^ 1][0] + c * 1024);
        async_copy16(gb + c * 8 * sA, (char*)&Bs[buf ^ 1][0] + c * 1024);
      }
    }
#pragma unroll
    for (int ks = 0; ks < 2; ++ks) {
      f16x8 af[4], bfr[4];
#pragma unroll
      for (int mi = 0; mi < 4; ++mi)
        af[mi] = *(const f16x8*)&As[buf][(arow + mi * 16) * 64 + ks * 32 + koff];
#pragma unroll
      for (int ni = 0; ni < 4; ++ni)
        bfr[ni] = *(const f16x8*)&Bs[buf][(brow + ni * 16) * 64 + ks * 32 + koff];
#pragma unroll
      for (int mi = 0; mi < 4; ++mi)
#pragma unroll
        for (int ni = 0; ni < 4; ++ni)
          acc[mi][ni] = __builtin_amdgcn_mfma_f32_16x16x32_f16(
              af[mi], bfr[ni], acc[mi][ni], 0, 0, 0);
    }
    __syncthreads();
  }

  const int grow0 = tm * 128 + wm * 64 + (l >> 4) * 4;
  const int gcol0 = tn * 128 + wn * 64 + (l & 15);
#pragma unroll
  for (int ni = 0; ni < 4; ++ni) {
    const int col = gcol0 + ni * 16;
    const float bv = bias[col];
#pragma unroll
    for (int mi = 0; mi < 4; ++mi) {
      const int row = grow0 + mi * 16;
#pragma unroll
      for (int r = 0; r < 4; ++r) {
        float v = acc[mi][ni][r] + bv;
        if (RELU) v = fmaxf(v, 0.f);
        C[(size_t)(row + r) * N + col] = f2h(v);
      }
    }
  }
}

// ---- convex fixed-point (100 iters) + gather ----
// y-space: y_i <- min(y_i, 0.5*(y_{i-1}+y_{i+1})); result = y.
// Rows b0 (.x) and b0+1 (.y) packed per f32x2; 32 lanes per row-pair,
// 8 feats/lane -> 4 rows/wave. Native f32x2 arithmetic (compiler emits
// v_pk_add_f32/v_pk_mul_f32; NO inline asm -> clean regalloc, no spill).
__global__ __launch_bounds__(256) void convex_gather(
    const ushort* __restrict__ xqh, const int* __restrict__ idx,
    float* __restrict__ out) {
  const int l = threadIdx.x & 63;
  const int wv = threadIdx.x >> 6;
  const int li = l & 31;               // lane within row-pair
  const int half = l >> 5;             // which row-pair of this wave
  const int b0 = blockIdx.x * 16 + wv * 4 + half * 2;  // rows b0, b0+1

  f32x2 y[8];
  {
    const ushort* sa = xqh + (size_t)b0 * 256 + li * 8;
    f16x8 a = *reinterpret_cast<const f16x8*>(sa);
    f16x8 b = *reinterpret_cast<const f16x8*>(sa + 256);
#pragma unroll
    for (int j = 0; j < 8; ++j) {
      y[j].x = (float)a[j];
      y[j].y = (float)b[j];
    }
  }
  const int iiA = idx[b0];
  const int iiB = idx[b0 + 1];

  // hoisted bpermute byte-indices; cross-pair reads at the 31|32 seam are
  // masked by the sentinels (feats 0 and 255 never update: D rows are zero)
  const int upIdx = ((l - 1) & 63) * 4;
  const int dnIdx = ((l + 1) & 63) * 4;
  const float sL = (li == 0) ? 3.0e38f : 0.0f;
  const float sR = (li == 31) ? 3.0e38f : 0.0f;
  const f32x2 bLp = {sL, sL};
  const f32x2 bRp = {sR, sR};
  const f32x2 halfc = {0.5f, 0.5f};

#pragma unroll 2
  for (int it = 0; it < N_IT; ++it) {
    f32x2 Lv, Rv;
    Lv.x = __int_as_float(__builtin_amdgcn_ds_bpermute(upIdx, __float_as_int(y[7].x)));
    Lv.y = __int_as_float(__builtin_amdgcn_ds_bpermute(upIdx, __float_as_int(y[7].y)));
    Rv.x = __int_as_float(__builtin_amdgcn_ds_bpermute(dnIdx, __float_as_int(y[0].x)));
    Rv.y = __int_as_float(__builtin_amdgcn_ds_bpermute(dnIdx, __float_as_int(y[0].y)));
    Lv += bLp;
    Rv += bRp;
    f32x2 m[8];
    m[0] = (Lv + y[1]) * halfc;
#pragma unroll
    for (int t = 1; t < 7; ++t) m[t] = (y[t - 1] + y[t + 1]) * halfc;
    m[7] = (y[6] + Rv) * halfc;
#pragma unroll
    for (int t = 0; t < 8; ++t) {
      y[t].x = fminf(y[t].x, m[t].x);
      y[t].y = fminf(y[t].y, m[t].y);
    }
  }

  // gather feature iiA (row b0) / iiB (row b0+1): cndmask tree + lane pick
  float ya[8], yb[8];
#pragma unroll
  for (int t = 0; t < 8; ++t) { ya[t] = y[t].x; yb[t] = y[t].y; }
  const int selA = iiA & 7, selB = iiB & 7;
#pragma unroll
  for (int step = 4; step >= 1; step >>= 1) {
#pragma unroll
    for (int k = 0; k < 4; ++k) {
      if (k < step) {
        ya[k] = (selA & step) ? ya[k + step] : ya[k];
        yb[k] = (selB & step) ? yb[k + step] : yb[k];
      }
    }
  }
  float vA = __shfl(ya[0], (l & 32) | (iiA >> 3));
  float vB = __shfl(yb[0], (l & 32) | (iiB >> 3));
  if (li == 0) {
    out[b0] = vA;
    out[b0 + 1] = vB;
  }
}

extern "C" void kernel_launch(void* const* d_in, const int* in_sizes, int n_in,
                              void* d_out, int out_size, void* d_ws, size_t ws_size,
                              hipStream_t stream) {
  const float* x = (const float*)d_in[0];
  const float* W1 = (const float*)d_in[1];
  const float* b1 = (const float*)d_in[2];
  const float* W2 = (const float*)d_in[3];
  const float* b2 = (const float*)d_in[4];
  float* out = (float*)d_out;

  // workspace layout (16B-aligned)
  char* ws = (char*)d_ws;
  ushort* xh  = (ushort*)ws;                    // 16,777,216 B  x f16 [B,256]
  ushort* w1h = (ushort*)(ws + 16777216);       //    524,288 B
  ushort* w2h = (ushort*)(ws + 17301504);       //    524,288 B
  int*    idx = (int*)  (ws + 17825792);        //    131,072 B
  ushort* xqh = (ushort*)(ws + 17956864);       // 16,777,216 B  x_ f16 [B,256]
  ushort* h   = (ushort*)(ws + 34734080);       // chunk*2048 B  h f16 [chunk,1024]

  const size_t fixed = 34734080;
  int chunk = 2048;
  if (ws_size >= fixed + (size_t)32768 * 2048) chunk = 32768;
  else if (ws_size >= fixed + (size_t)16384 * 2048) chunk = 16384;
  else if (ws_size >= fixed + (size_t)8192 * 2048) chunk = 8192;
  else if (ws_size >= fixed + (size_t)4096 * 2048) chunk = 4096;

  prep_kernel<<<8448, 256, 0, stream>>>(x, W1, W2, xh, w1h, w2h, idx);

  for (int m0 = 0; m0 < B_ROWS; m0 += chunk) {
    int curM = (B_ROWS - m0 < chunk) ? (B_ROWS - m0) : chunk;
    dim3 g1((curM / 128) * (N_HID / 128));
    gemm_bt<1><<<g1, 256, 0, stream>>>(xh + (size_t)m0 * 256, w1h, b1, h,
                                       curM, N_HID, N_INP, N_HID / 128);
    dim3 g2((curM / 128) * (NF / 128));
    gemm_bt<0><<<g2, 256, 0, stream>>>(h, w2h, b2, xqh + (size_t)m0 * 256,
                                       curM, NF, N_HID, NF / 128);
  }
  convex_gather<<<B_ROWS / 16, 256, 0, stream>>>(xqh, idx, out);
}